// Round 1
// baseline (443.802 us; speedup 1.0000x reference)
//
#include <hip/hip_runtime.h>
#include <hip/hip_bf16.h>
#include <stdint.h>

#define N_ROWS 4096
#define Z_DIM  2048
#define TOT    8192           // 2N rows of reps
#define TILE   128
#define BK     32
#define INV_T  2.0f           // 1/temperature

typedef __attribute__((ext_vector_type(8))) __bf16 bf16x8;
typedef __attribute__((ext_vector_type(8))) unsigned short ushort8;
typedef __attribute__((ext_vector_type(4))) float floatx4;

// round-to-nearest-even f32 -> bf16 bits (inputs are finite, no NaN handling)
__device__ __forceinline__ unsigned short f2bf(float f) {
    union { float f; unsigned int u; } v; v.f = f;
    unsigned int u = v.u;
    return (unsigned short)((u + 0x7FFFu + ((u >> 16) & 1u)) >> 16);
}

#define GLOAD16(g, l)                                                   \
    __builtin_amdgcn_global_load_lds(                                   \
        (const __attribute__((address_space(1))) unsigned int*)(g),     \
        (__attribute__((address_space(3))) unsigned int*)(l), 16, 0, 0)

// ---------------- kernel 1: row-normalize to bf16, compute pos ----------------
__global__ __launch_bounds__(256) void normalize_kernel(
    const float* __restrict__ z1, const float* __restrict__ z2,
    unsigned short* __restrict__ reps, float* __restrict__ pos)
{
    const int row  = blockIdx.x;          // 0..4095
    const int tid  = threadIdx.x;         // 0..255, 8 floats each
    const int lane = tid & 63, wave = tid >> 6;

    const float4* p1 = (const float4*)(z1 + (size_t)row * Z_DIM);
    const float4* p2 = (const float4*)(z2 + (size_t)row * Z_DIM);
    float4 x0 = p1[tid * 2], x1 = p1[tid * 2 + 1];
    float4 y0 = p2[tid * 2], y1 = p2[tid * 2 + 1];

    float s1 = x0.x*x0.x + x0.y*x0.y + x0.z*x0.z + x0.w*x0.w
             + x1.x*x1.x + x1.y*x1.y + x1.z*x1.z + x1.w*x1.w;
    float s2 = y0.x*y0.x + y0.y*y0.y + y0.z*y0.z + y0.w*y0.w
             + y1.x*y1.x + y1.y*y1.y + y1.z*y1.z + y1.w*y1.w;
    float dd = x0.x*y0.x + x0.y*y0.y + x0.z*y0.z + x0.w*y0.w
             + x1.x*y1.x + x1.y*y1.y + x1.z*y1.z + x1.w*y1.w;

    #pragma unroll
    for (int m = 1; m < 64; m <<= 1) {
        s1 += __shfl_xor(s1, m);
        s2 += __shfl_xor(s2, m);
        dd += __shfl_xor(dd, m);
    }
    __shared__ float red[3][4];
    if (lane == 0) { red[0][wave] = s1; red[1][wave] = s2; red[2][wave] = dd; }
    __syncthreads();
    s1 = red[0][0] + red[0][1] + red[0][2] + red[0][3];
    s2 = red[1][0] + red[1][1] + red[1][2] + red[1][3];
    dd = red[2][0] + red[2][1] + red[2][2] + red[2][3];

    const float inv1 = rsqrtf(s1), inv2 = rsqrtf(s2);
    if (tid == 0) {
        float p = dd * inv1 * inv2 * INV_T;
        pos[row] = p;
        pos[row + N_ROWS] = p;
    }

    ushort8 oa, ob;
    oa[0]=f2bf(x0.x*inv1); oa[1]=f2bf(x0.y*inv1); oa[2]=f2bf(x0.z*inv1); oa[3]=f2bf(x0.w*inv1);
    oa[4]=f2bf(x1.x*inv1); oa[5]=f2bf(x1.y*inv1); oa[6]=f2bf(x1.z*inv1); oa[7]=f2bf(x1.w*inv1);
    ob[0]=f2bf(y0.x*inv2); ob[1]=f2bf(y0.y*inv2); ob[2]=f2bf(y0.z*inv2); ob[3]=f2bf(y0.w*inv2);
    ob[4]=f2bf(y1.x*inv2); ob[5]=f2bf(y1.y*inv2); ob[6]=f2bf(y1.z*inv2); ob[7]=f2bf(y1.w*inv2);
    *(ushort8*)(reps + (size_t)row * Z_DIM + tid * 8) = oa;
    *(ushort8*)(reps + (size_t)(N_ROWS + row) * Z_DIM + tid * 8) = ob;
}

// ---------------- kernel 2: S = reps@reps^T, rowsum of exp(2*S) excl diag ----
// m97 recipe: 128x128 tile, BK=32, 4 waves each computing a 64x64 quadrant as
// a 4x4 grid of 16x16x32 bf16 MFMAs; staging via global_load_lds width=16.
__global__ __launch_bounds__(256) void simclr_gemm(
    const unsigned short* __restrict__ reps, float* __restrict__ rowsum)
{
    __shared__ __align__(16) unsigned short lA[TILE * BK];
    __shared__ __align__(16) unsigned short lB[TILE * BK];

    const int bi = blockIdx.y, bj = blockIdx.x;
    const int tid  = threadIdx.x;
    const int lane = tid & 63, wave = tid >> 6;
    const int wr = wave >> 1, wc = wave & 1;       // 2x2 waves over 128x128
    const int quad = lane >> 4, l16 = lane & 15;
    const int row0 = bi * TILE, col0 = bj * TILE;

    floatx4 acc[4][4];
    #pragma unroll
    for (int i = 0; i < 4; ++i)
        #pragma unroll
        for (int j = 0; j < 4; ++j)
            acc[i][j] = floatx4{0.f, 0.f, 0.f, 0.f};

    // staging: chunk c (0..511) = 16B at LDS byte c*16 = reps[row0 + c/4][k0 + (c%4)*8 ..+8]
    // lane layout satisfies the wave-uniform-base + lane*16 requirement.
    const int c0 = tid, c1 = tid + 256;
    const unsigned short* gA0 = reps + (size_t)(row0 + (c0 >> 2)) * Z_DIM + (c0 & 3) * 8;
    const unsigned short* gA1 = reps + (size_t)(row0 + (c1 >> 2)) * Z_DIM + (c1 & 3) * 8;
    const unsigned short* gB0 = reps + (size_t)(col0 + (c0 >> 2)) * Z_DIM + (c0 & 3) * 8;
    const unsigned short* gB1 = reps + (size_t)(col0 + (c1 >> 2)) * Z_DIM + (c1 & 3) * 8;
    unsigned short* lA0 = &lA[c0 * 8];
    unsigned short* lA1 = &lA[c1 * 8];
    unsigned short* lB0 = &lB[c0 * 8];
    unsigned short* lB1 = &lB[c1 * 8];

    for (int k0 = 0; k0 < Z_DIM; k0 += BK) {
        __syncthreads();                  // previous tile fully consumed
        GLOAD16(gA0 + k0, lA0);
        GLOAD16(gA1 + k0, lA1);
        GLOAD16(gB0 + k0, lB0);
        GLOAD16(gB1 + k0, lB1);
        __syncthreads();                  // drains vmcnt -> tiles visible

        bf16x8 af[4], bf[4];
        #pragma unroll
        for (int i = 0; i < 4; ++i) {
            af[i] = *(const bf16x8*)&lA[(wr * 64 + i * 16 + l16) * BK + quad * 8];
            bf[i] = *(const bf16x8*)&lB[(wc * 64 + i * 16 + l16) * BK + quad * 8];
        }
        #pragma unroll
        for (int i = 0; i < 4; ++i)
            #pragma unroll
            for (int j = 0; j < 4; ++j)
                acc[i][j] = __builtin_amdgcn_mfma_f32_16x16x32_bf16(
                    af[i], bf[j], acc[i][j], 0, 0, 0);
    }

    // Epilogue: C/D layout col = lane&15, row = quad*4 + reg (m89-verified).
    // logits bounded by |1/T|=2 -> no max tracking needed for logsumexp.
    #pragma unroll
    for (int i = 0; i < 4; ++i) {
        const int rbase = row0 + wr * 64 + i * 16 + quad * 4;
        float s[4] = {0.f, 0.f, 0.f, 0.f};
        #pragma unroll
        for (int j = 0; j < 4; ++j) {
            const int c = col0 + wc * 64 + j * 16 + l16;
            #pragma unroll
            for (int r = 0; r < 4; ++r) {
                float e = __expf(INV_T * acc[i][j][r]);
                if (rbase + r == c) e = 0.f;   // exclude self-similarity
                s[r] += e;
            }
        }
        #pragma unroll
        for (int r = 0; r < 4; ++r) {
            #pragma unroll
            for (int m = 1; m < 16; m <<= 1) s[r] += __shfl_xor(s[r], m);
        }
        if (l16 == 0) {
            #pragma unroll
            for (int r = 0; r < 4; ++r)
                atomicAdd(&rowsum[rbase + r], s[r]);
        }
    }
}

// ---------------- kernel 3: mean(log(rowsum) - pos) ----------------
__global__ __launch_bounds__(256) void finalize_kernel(
    const float* __restrict__ rowsum, const float* __restrict__ pos,
    float* __restrict__ out)
{
    const int tid = threadIdx.x;
    const int lane = tid & 63, wave = tid >> 6;
    float s = 0.f;
    for (int r = tid; r < TOT; r += 256) s += logf(rowsum[r]) - pos[r];
    #pragma unroll
    for (int m = 1; m < 64; m <<= 1) s += __shfl_xor(s, m);
    __shared__ float red[4];
    if (lane == 0) red[wave] = s;
    __syncthreads();
    if (tid == 0) out[0] = (red[0] + red[1] + red[2] + red[3]) * (1.0f / TOT);
}

extern "C" void kernel_launch(void* const* d_in, const int* in_sizes, int n_in,
                              void* d_out, int out_size, void* d_ws, size_t ws_size,
                              hipStream_t stream)
{
    const float* z1 = (const float*)d_in[0];
    const float* z2 = (const float*)d_in[1];
    float* out = (float*)d_out;

    char* w = (char*)d_ws;
    unsigned short* reps = (unsigned short*)w;                       // 32 MiB bf16 [8192][2048]
    float* pos    = (float*)(w + (size_t)TOT * Z_DIM * 2);           // 32 KiB
    float* rowsum = pos + TOT;                                       // 32 KiB

    hipMemsetAsync(rowsum, 0, TOT * sizeof(float), stream);
    normalize_kernel<<<N_ROWS, 256, 0, stream>>>(z1, z2, reps, pos);
    dim3 grid(TOT / TILE, TOT / TILE);
    simclr_gemm<<<grid, 256, 0, stream>>>(reps, rowsum);
    finalize_kernel<<<1, 256, 0, stream>>>(rowsum, pos, out);
}

// Round 2
// 270.623 us; speedup vs baseline: 1.6399x; 1.6399x over previous
//
#include <hip/hip_runtime.h>
#include <hip/hip_bf16.h>
#include <stdint.h>

#define N_ROWS 4096
#define Z_DIM  2048
#define TOT    8192           // 2N rows of reps
#define TILE   128
#define BK     32
#define NT     (TOT / TILE)   // 64 tile-columns
#define NBLK   (NT * (NT + 1) / 2)   // 2080 triangular blocks
#define INV_T  2.0f           // 1/temperature

typedef __attribute__((ext_vector_type(8))) __bf16 bf16x8;
typedef __attribute__((ext_vector_type(8))) unsigned short ushort8;
typedef __attribute__((ext_vector_type(4))) float floatx4;

// round-to-nearest-even f32 -> bf16 bits (inputs are finite, no NaN handling)
__device__ __forceinline__ unsigned short f2bf(float f) {
    union { float f; unsigned int u; } v; v.f = f;
    unsigned int u = v.u;
    return (unsigned short)((u + 0x7FFFu + ((u >> 16) & 1u)) >> 16);
}

#define GLOAD16(g, l)                                                   \
    __builtin_amdgcn_global_load_lds(                                   \
        (const __attribute__((address_space(1))) unsigned int*)(g),     \
        (__attribute__((address_space(3))) unsigned int*)(l), 16, 0, 0)

// ---------------- kernel 1: row-normalize to bf16, compute pos ----------------
__global__ __launch_bounds__(256) void normalize_kernel(
    const float* __restrict__ z1, const float* __restrict__ z2,
    unsigned short* __restrict__ reps, float* __restrict__ pos)
{
    const int row  = blockIdx.x;          // 0..4095
    const int tid  = threadIdx.x;         // 0..255, 8 floats each
    const int lane = tid & 63, wave = tid >> 6;

    const float4* p1 = (const float4*)(z1 + (size_t)row * Z_DIM);
    const float4* p2 = (const float4*)(z2 + (size_t)row * Z_DIM);
    float4 x0 = p1[tid * 2], x1 = p1[tid * 2 + 1];
    float4 y0 = p2[tid * 2], y1 = p2[tid * 2 + 1];

    float s1 = x0.x*x0.x + x0.y*x0.y + x0.z*x0.z + x0.w*x0.w
             + x1.x*x1.x + x1.y*x1.y + x1.z*x1.z + x1.w*x1.w;
    float s2 = y0.x*y0.x + y0.y*y0.y + y0.z*y0.z + y0.w*y0.w
             + y1.x*y1.x + y1.y*y1.y + y1.z*y1.z + y1.w*y1.w;
    float dd = x0.x*y0.x + x0.y*y0.y + x0.z*y0.z + x0.w*y0.w
             + x1.x*y1.x + x1.y*y1.y + x1.z*y1.z + x1.w*y1.w;

    #pragma unroll
    for (int m = 1; m < 64; m <<= 1) {
        s1 += __shfl_xor(s1, m);
        s2 += __shfl_xor(s2, m);
        dd += __shfl_xor(dd, m);
    }
    __shared__ float red[3][4];
    if (lane == 0) { red[0][wave] = s1; red[1][wave] = s2; red[2][wave] = dd; }
    __syncthreads();
    s1 = red[0][0] + red[0][1] + red[0][2] + red[0][3];
    s2 = red[1][0] + red[1][1] + red[1][2] + red[1][3];
    dd = red[2][0] + red[2][1] + red[2][2] + red[2][3];

    const float inv1 = rsqrtf(s1), inv2 = rsqrtf(s2);
    if (tid == 0) {
        float p = dd * inv1 * inv2 * INV_T;
        pos[row] = p;
        pos[row + N_ROWS] = p;
    }

    ushort8 oa, ob;
    oa[0]=f2bf(x0.x*inv1); oa[1]=f2bf(x0.y*inv1); oa[2]=f2bf(x0.z*inv1); oa[3]=f2bf(x0.w*inv1);
    oa[4]=f2bf(x1.x*inv1); oa[5]=f2bf(x1.y*inv1); oa[6]=f2bf(x1.z*inv1); oa[7]=f2bf(x1.w*inv1);
    ob[0]=f2bf(y0.x*inv2); ob[1]=f2bf(y0.y*inv2); ob[2]=f2bf(y0.z*inv2); ob[3]=f2bf(y0.w*inv2);
    ob[4]=f2bf(y1.x*inv2); ob[5]=f2bf(y1.y*inv2); ob[6]=f2bf(y1.z*inv2); ob[7]=f2bf(y1.w*inv2);
    *(ushort8*)(reps + (size_t)row * Z_DIM + tid * 8) = oa;
    *(ushort8*)(reps + (size_t)(N_ROWS + row) * Z_DIM + tid * 8) = ob;
}

// ---------------- kernel 2: triangular S = reps@reps^T, rowsums of exp ------
// Symmetry: only tiles bi <= bj are computed; off-diagonal tiles contribute
// their exp values to BOTH rowsum[row] (16-lane reduce) and rowsum[col]
// (cross-quad reduce). LDS uses an XOR swizzle (slot = kc ^ ((row>>1)&3)) so
// fragment ds_read_b128 lands 2 lanes/bank (free per m136) instead of 8-way.
__global__ __launch_bounds__(256) void simclr_gemm(
    const unsigned short* __restrict__ reps, float* __restrict__ rowsum)
{
    __shared__ __align__(16) unsigned short lA[TILE * BK];
    __shared__ __align__(16) unsigned short lB[TILE * BK];

    // decode linear block id -> lower-triangle (r >= c); bi = c, bj = r
    const int t = blockIdx.x;
    int r = (int)((sqrtf(8.0f * (float)t + 1.0f) - 1.0f) * 0.5f);
    while ((r + 1) * (r + 2) / 2 <= t) ++r;
    while (r * (r + 1) / 2 > t) --r;
    const int bi = t - r * (r + 1) / 2;   // <= bj
    const int bj = r;
    const bool diag = (bi == bj);

    const int tid  = threadIdx.x;
    const int lane = tid & 63, wave = tid >> 6;
    const int wr = wave >> 1, wc = wave & 1;       // 2x2 waves over 128x128
    const int quad = lane >> 4, l16 = lane & 15;
    const int sw   = (l16 >> 1) & 3;               // row-derived XOR swizzle
    const int row0 = bi * TILE, col0 = bj * TILE;

    floatx4 acc[4][4];
    #pragma unroll
    for (int i = 0; i < 4; ++i)
        #pragma unroll
        for (int j = 0; j < 4; ++j)
            acc[i][j] = floatx4{0.f, 0.f, 0.f, 0.f};

    // staging: LDS slot c holds global chunk kc = (c&3) ^ ((row>>1)&3) of row c>>2.
    // LDS dest stays wave-uniform-base + lane*16 (required by global_load_lds).
    const int c0 = tid, c1 = tid + 256;
    const int r0s = c0 >> 2, k0s = (c0 & 3) ^ ((r0s >> 1) & 3);
    const int r1s = c1 >> 2, k1s = (c1 & 3) ^ ((r1s >> 1) & 3);
    const unsigned short* gA0 = reps + (size_t)(row0 + r0s) * Z_DIM + k0s * 8;
    const unsigned short* gA1 = reps + (size_t)(row0 + r1s) * Z_DIM + k1s * 8;
    const unsigned short* gB0 = reps + (size_t)(col0 + r0s) * Z_DIM + k0s * 8;
    const unsigned short* gB1 = reps + (size_t)(col0 + r1s) * Z_DIM + k1s * 8;
    unsigned short* lA0 = &lA[c0 * 8];
    unsigned short* lA1 = &lA[c1 * 8];
    unsigned short* lB0 = &lB[c0 * 8];
    unsigned short* lB1 = &lB[c1 * 8];

    for (int k0 = 0; k0 < Z_DIM; k0 += BK) {
        __syncthreads();                  // previous tile fully consumed
        GLOAD16(gA0 + k0, lA0);
        GLOAD16(gA1 + k0, lA1);
        GLOAD16(gB0 + k0, lB0);
        GLOAD16(gB1 + k0, lB1);
        __syncthreads();                  // drains vmcnt -> tiles visible

        bf16x8 af[4], bf[4];
        #pragma unroll
        for (int i = 0; i < 4; ++i) {
            af[i] = *(const bf16x8*)&lA[(wr * 64 + i * 16 + l16) * BK + ((quad ^ sw) * 8)];
            bf[i] = *(const bf16x8*)&lB[(wc * 64 + i * 16 + l16) * BK + ((quad ^ sw) * 8)];
        }
        #pragma unroll
        for (int i = 0; i < 4; ++i)
            #pragma unroll
            for (int j = 0; j < 4; ++j)
                acc[i][j] = __builtin_amdgcn_mfma_f32_16x16x32_bf16(
                    af[i], bf[j], acc[i][j], 0, 0, 0);
    }

    // Epilogue: C/D layout col = lane&15, row = quad*4 + reg (m89-verified).
    // |logits| <= 2 -> no max tracking needed. Row sums always; column sums
    // only for off-diagonal blocks (symmetry credit to the mirrored rows).
    float scol[4] = {0.f, 0.f, 0.f, 0.f};
    #pragma unroll
    for (int i = 0; i < 4; ++i) {
        const int rbase = row0 + wr * 64 + i * 16 + quad * 4;
        float srow[4] = {0.f, 0.f, 0.f, 0.f};
        #pragma unroll
        for (int j = 0; j < 4; ++j) {
            const int c = col0 + wc * 64 + j * 16 + l16;
            #pragma unroll
            for (int rr = 0; rr < 4; ++rr) {
                float e = __expf(INV_T * acc[i][j][rr]);
                if (diag && (rbase + rr == c)) e = 0.f;  // exclude self-sim
                srow[rr] += e;
                scol[j]  += e;
            }
        }
        #pragma unroll
        for (int rr = 0; rr < 4; ++rr) {
            #pragma unroll
            for (int m = 1; m < 16; m <<= 1) srow[rr] += __shfl_xor(srow[rr], m);
        }
        if (l16 == 0) {
            #pragma unroll
            for (int rr = 0; rr < 4; ++rr)
                atomicAdd(&rowsum[rbase + rr], srow[rr]);
        }
    }
    if (!diag) {
        #pragma unroll
        for (int j = 0; j < 4; ++j) {
            scol[j] += __shfl_xor(scol[j], 16);
            scol[j] += __shfl_xor(scol[j], 32);
        }
        if (quad == 0) {
            #pragma unroll
            for (int j = 0; j < 4; ++j)
                atomicAdd(&rowsum[col0 + wc * 64 + j * 16 + l16], scol[j]);
        }
    }
}

// ---------------- kernel 3: mean(log(rowsum) - pos) ----------------
__global__ __launch_bounds__(1024) void finalize_kernel(
    const float* __restrict__ rowsum, const float* __restrict__ pos,
    float* __restrict__ out)
{
    const int tid = threadIdx.x;
    const int lane = tid & 63, wave = tid >> 6;
    float s = 0.f;
    for (int r = tid; r < TOT; r += 1024) s += logf(rowsum[r]) - pos[r];
    #pragma unroll
    for (int m = 1; m < 64; m <<= 1) s += __shfl_xor(s, m);
    __shared__ float red[16];
    if (lane == 0) red[wave] = s;
    __syncthreads();
    if (tid == 0) {
        float t = 0.f;
        #pragma unroll
        for (int w = 0; w < 16; ++w) t += red[w];
        out[0] = t * (1.0f / TOT);
    }
}

extern "C" void kernel_launch(void* const* d_in, const int* in_sizes, int n_in,
                              void* d_out, int out_size, void* d_ws, size_t ws_size,
                              hipStream_t stream)
{
    const float* z1 = (const float*)d_in[0];
    const float* z2 = (const float*)d_in[1];
    float* out = (float*)d_out;

    char* w = (char*)d_ws;
    unsigned short* reps = (unsigned short*)w;                       // 32 MiB bf16 [8192][2048]
    float* pos    = (float*)(w + (size_t)TOT * Z_DIM * 2);           // 32 KiB
    float* rowsum = pos + TOT;                                       // 32 KiB

    hipMemsetAsync(rowsum, 0, TOT * sizeof(float), stream);
    normalize_kernel<<<N_ROWS, 256, 0, stream>>>(z1, z2, reps, pos);
    simclr_gemm<<<NBLK, 256, 0, stream>>>(reps, rowsum);
    finalize_kernel<<<1, 1024, 0, stream>>>(rowsum, pos, out);
}

// Round 3
// 194.252 us; speedup vs baseline: 2.2847x; 1.3932x over previous
//
#include <hip/hip_runtime.h>
#include <stdint.h>

#define N_ROWS 4096
#define Z_DIM  2048
#define TOT    8192           // 2N rows of reps
#define TILE   128
#define BKB    128            // K fp8 elements (bytes) per staging round
#define NT     (TOT / TILE)   // 64 tile-columns
#define NBLK   (NT * (NT + 1) / 2)   // 2080 triangular blocks
#define INV_T  2.0f           // 1/temperature
#define SCL    16.0f          // fp8 pre-scale; logits = acc * INV_T / (SCL*SCL)

typedef __attribute__((ext_vector_type(4))) int   intx4;
typedef __attribute__((ext_vector_type(8))) int   intx8;
typedef __attribute__((ext_vector_type(4))) float floatx4;

#define GLOAD16(g, l)                                                   \
    __builtin_amdgcn_global_load_lds(                                   \
        (const __attribute__((address_space(1))) unsigned int*)(g),     \
        (__attribute__((address_space(3))) unsigned int*)(l), 16, 0, 0)

// ---------------- kernel 1: row-normalize to fp8(e4m3, x16), pos, zero rowsum
__global__ __launch_bounds__(256) void normalize_kernel(
    const float* __restrict__ z1, const float* __restrict__ z2,
    unsigned char* __restrict__ reps, float* __restrict__ pos,
    float* __restrict__ rowsum)
{
    const int row  = blockIdx.x;          // 0..4095
    const int tid  = threadIdx.x;         // 0..255, 8 floats each
    const int lane = tid & 63, wave = tid >> 6;

    if (row < TOT / 256) rowsum[row * 256 + tid] = 0.f;   // fold in memset

    const float4* p1 = (const float4*)(z1 + (size_t)row * Z_DIM);
    const float4* p2 = (const float4*)(z2 + (size_t)row * Z_DIM);
    float4 x0 = p1[tid * 2], x1 = p1[tid * 2 + 1];
    float4 y0 = p2[tid * 2], y1 = p2[tid * 2 + 1];

    float s1 = x0.x*x0.x + x0.y*x0.y + x0.z*x0.z + x0.w*x0.w
             + x1.x*x1.x + x1.y*x1.y + x1.z*x1.z + x1.w*x1.w;
    float s2 = y0.x*y0.x + y0.y*y0.y + y0.z*y0.z + y0.w*y0.w
             + y1.x*y1.x + y1.y*y1.y + y1.z*y1.z + y1.w*y1.w;
    float dd = x0.x*y0.x + x0.y*y0.y + x0.z*y0.z + x0.w*y0.w
             + x1.x*y1.x + x1.y*y1.y + x1.z*y1.z + x1.w*y1.w;

    #pragma unroll
    for (int m = 1; m < 64; m <<= 1) {
        s1 += __shfl_xor(s1, m);
        s2 += __shfl_xor(s2, m);
        dd += __shfl_xor(dd, m);
    }
    __shared__ float red[3][4];
    if (lane == 0) { red[0][wave] = s1; red[1][wave] = s2; red[2][wave] = dd; }
    __syncthreads();
    s1 = red[0][0] + red[0][1] + red[0][2] + red[0][3];
    s2 = red[1][0] + red[1][1] + red[1][2] + red[1][3];
    dd = red[2][0] + red[2][1] + red[2][2] + red[2][3];

    const float inv1 = rsqrtf(s1), inv2 = rsqrtf(s2);
    if (tid == 0) {
        float p = dd * inv1 * inv2 * INV_T;   // pos in full fp32 precision
        pos[row] = p;
        pos[row + N_ROWS] = p;
    }

    // fp8 e4m3 encode of (normalized * 16): well inside normal range.
    const float a = inv1 * SCL, b = inv2 * SCL;
    unsigned int a0 = 0, a1 = 0, b0 = 0, b1 = 0;
    a0 = __builtin_amdgcn_cvt_pk_fp8_f32(x0.x * a, x0.y * a, a0, false);
    a0 = __builtin_amdgcn_cvt_pk_fp8_f32(x0.z * a, x0.w * a, a0, true);
    a1 = __builtin_amdgcn_cvt_pk_fp8_f32(x1.x * a, x1.y * a, a1, false);
    a1 = __builtin_amdgcn_cvt_pk_fp8_f32(x1.z * a, x1.w * a, a1, true);
    b0 = __builtin_amdgcn_cvt_pk_fp8_f32(y0.x * b, y0.y * b, b0, false);
    b0 = __builtin_amdgcn_cvt_pk_fp8_f32(y0.z * b, y0.w * b, b0, true);
    b1 = __builtin_amdgcn_cvt_pk_fp8_f32(y1.x * b, y1.y * b, b1, false);
    b1 = __builtin_amdgcn_cvt_pk_fp8_f32(y1.z * b, y1.w * b, b1, true);
    uint2 pa = {a0, a1}, pb = {b0, b1};
    *(uint2*)(reps + (size_t)row * Z_DIM + tid * 8) = pa;
    *(uint2*)(reps + (size_t)(N_ROWS + row) * Z_DIM + tid * 8) = pb;
}

// ---------------- kernel 2: triangular S = reps@reps^T via MX-fp8 K=128 -----
// Tile 128x128, BK=128 fp8 bytes. 2x2 waves, each a 4x4 grid of
// mfma_scale_f32_16x16x128_f8f6f4 (unit E8M0 scales; descale folded into exp).
// LDS slot = kc ^ (row&7) at 16B granularity: per-16-lane phase each chunk
// group gets 2 lanes (round-2-verified conflict-free pattern).
__global__ __launch_bounds__(256) void simclr_gemm(
    const unsigned char* __restrict__ reps, float* __restrict__ rowsum)
{
    __shared__ __align__(16) unsigned char lA[TILE * BKB];   // 16 KiB
    __shared__ __align__(16) unsigned char lB[TILE * BKB];   // 16 KiB

    // decode linear block id -> lower-triangle (r >= c); bi = c, bj = r
    const int t = blockIdx.x;
    int r = (int)((sqrtf(8.0f * (float)t + 1.0f) - 1.0f) * 0.5f);
    while ((r + 1) * (r + 2) / 2 <= t) ++r;
    while (r * (r + 1) / 2 > t) --r;
    const int bi = t - r * (r + 1) / 2;   // <= bj
    const int bj = r;
    const bool diag = (bi == bj);

    const int tid  = threadIdx.x;
    const int lane = tid & 63, wave = tid >> 6;
    const int wr = wave >> 1, wc = wave & 1;       // 2x2 waves over 128x128
    const int quad = lane >> 4, l16 = lane & 15;
    const int sw   = l16 & 7;                      // row-derived XOR swizzle
    const int row0 = bi * TILE, col0 = bj * TILE;

    floatx4 acc[4][4];
    #pragma unroll
    for (int i = 0; i < 4; ++i)
        #pragma unroll
        for (int j = 0; j < 4; ++j)
            acc[i][j] = floatx4{0.f, 0.f, 0.f, 0.f};

    // staging: 1024 chunks of 16B per tile; thread handles chunks tid+q*256.
    // LDS slot c holds global 16B-chunk ((c&7) ^ ((c>>3)&7)) of row c>>3.
    const unsigned char* gA[4]; const unsigned char* gB[4];
    unsigned char* lAp[4]; unsigned char* lBp[4];
    #pragma unroll
    for (int q = 0; q < 4; ++q) {
        const int c = q * 256 + tid;
        const int srow = c >> 3, gkc = (c & 7) ^ (srow & 7);
        gA[q] = reps + (size_t)(row0 + srow) * Z_DIM + gkc * 16;
        gB[q] = reps + (size_t)(col0 + srow) * Z_DIM + gkc * 16;
        lAp[q] = &lA[c * 16];
        lBp[q] = &lB[c * 16];
    }

    for (int k0 = 0; k0 < Z_DIM; k0 += BKB) {
        __syncthreads();                  // previous tile fully consumed
        #pragma unroll
        for (int q = 0; q < 4; ++q) GLOAD16(gA[q] + k0, lAp[q]);
        #pragma unroll
        for (int q = 0; q < 4; ++q) GLOAD16(gB[q] + k0, lBp[q]);
        __syncthreads();                  // drains vmcnt -> tiles visible

        // fragment: elem k = quad*32 + j (j over 32 consecutive fp8 bytes)
        intx8 af[4], bf[4];
        #pragma unroll
        for (int i = 0; i < 4; ++i) {
            const int ar = (wr * 64 + i * 16 + l16) * BKB;
            const int br = (wc * 64 + i * 16 + l16) * BKB;
            intx4 alo = *(const intx4*)&lA[ar + (((quad * 2)     ^ sw) << 4)];
            intx4 ahi = *(const intx4*)&lA[ar + (((quad * 2 + 1) ^ sw) << 4)];
            intx4 blo = *(const intx4*)&lB[br + (((quad * 2)     ^ sw) << 4)];
            intx4 bhi = *(const intx4*)&lB[br + (((quad * 2 + 1) ^ sw) << 4)];
            af[i] = intx8{alo[0], alo[1], alo[2], alo[3], ahi[0], ahi[1], ahi[2], ahi[3]};
            bf[i] = intx8{blo[0], blo[1], blo[2], blo[3], bhi[0], bhi[1], bhi[2], bhi[3]};
        }
        #pragma unroll
        for (int i = 0; i < 4; ++i)
            #pragma unroll
            for (int j = 0; j < 4; ++j)
                acc[i][j] = __builtin_amdgcn_mfma_scale_f32_16x16x128_f8f6f4(
                    af[i], bf[j], acc[i][j],
                    0, 0,                      // cbsz=fp8(A), blgp=fp8(B)
                    0, 0x7F7F7F7Fu,            // opsel_a, scale_a = 1.0
                    0, 0x7F7F7F7Fu);           // opsel_b, scale_b = 1.0
    }

    // Epilogue: C/D layout col = lane&15, row = quad*4 + reg (shape-determined,
    // dtype-independent per m121-128). logit = acc * INV_T / SCL^2.
    const float descale = INV_T / (SCL * SCL);   // 1/128
    float scol[4] = {0.f, 0.f, 0.f, 0.f};
    #pragma unroll
    for (int i = 0; i < 4; ++i) {
        const int rbase = row0 + wr * 64 + i * 16 + quad * 4;
        float srow[4] = {0.f, 0.f, 0.f, 0.f};
        #pragma unroll
        for (int j = 0; j < 4; ++j) {
            const int c = col0 + wc * 64 + j * 16 + l16;
            #pragma unroll
            for (int rr = 0; rr < 4; ++rr) {
                float e = __expf(acc[i][j][rr] * descale);
                if (diag && (rbase + rr == c)) e = 0.f;  // exclude self-sim
                srow[rr] += e;
                scol[j]  += e;
            }
        }
        #pragma unroll
        for (int rr = 0; rr < 4; ++rr) {
            #pragma unroll
            for (int m = 1; m < 16; m <<= 1) srow[rr] += __shfl_xor(srow[rr], m);
        }
        if (l16 == 0) {
            #pragma unroll
            for (int rr = 0; rr < 4; ++rr)
                atomicAdd(&rowsum[rbase + rr], srow[rr]);
        }
    }
    if (!diag) {   // symmetry credit: column sums -> mirrored rows
        #pragma unroll
        for (int j = 0; j < 4; ++j) {
            scol[j] += __shfl_xor(scol[j], 16);
            scol[j] += __shfl_xor(scol[j], 32);
        }
        if (quad == 0) {
            #pragma unroll
            for (int j = 0; j < 4; ++j)
                atomicAdd(&rowsum[col0 + wc * 64 + j * 16 + l16], scol[j]);
        }
    }
}

// ---------------- kernel 3: mean(log(rowsum) - pos) ----------------
__global__ __launch_bounds__(1024) void finalize_kernel(
    const float* __restrict__ rowsum, const float* __restrict__ pos,
    float* __restrict__ out)
{
    const int tid = threadIdx.x;
    const int lane = tid & 63, wave = tid >> 6;
    float s = 0.f;
    for (int r = tid; r < TOT; r += 1024) s += logf(rowsum[r]) - pos[r];
    #pragma unroll
    for (int m = 1; m < 64; m <<= 1) s += __shfl_xor(s, m);
    __shared__ float red[16];
    if (lane == 0) red[wave] = s;
    __syncthreads();
    if (tid == 0) {
        float t = 0.f;
        #pragma unroll
        for (int w = 0; w < 16; ++w) t += red[w];
        out[0] = t * (1.0f / TOT);
    }
}

extern "C" void kernel_launch(void* const* d_in, const int* in_sizes, int n_in,
                              void* d_out, int out_size, void* d_ws, size_t ws_size,
                              hipStream_t stream)
{
    const float* z1 = (const float*)d_in[0];
    const float* z2 = (const float*)d_in[1];
    float* out = (float*)d_out;

    char* w = (char*)d_ws;
    unsigned char* reps = (unsigned char*)w;                 // 16 MiB fp8 [8192][2048]
    float* pos    = (float*)(w + (size_t)TOT * Z_DIM);       // 32 KiB
    float* rowsum = pos + TOT;                               // 32 KiB

    normalize_kernel<<<N_ROWS, 256, 0, stream>>>(z1, z2, reps, pos, rowsum);
    simclr_gemm<<<NBLK, 256, 0, stream>>>(reps, rowsum);
    finalize_kernel<<<1, 1024, 0, stream>>>(rowsum, pos, out);
}

// Round 4
// 184.559 us; speedup vs baseline: 2.4047x; 1.0525x over previous
//
#include <hip/hip_runtime.h>
#include <stdint.h>

#define N_ROWS 4096
#define Z_DIM  2048
#define TOT    8192           // 2N rows of reps
#define TILE   128
#define BKB    128            // K fp8 bytes per staging round
#define NITER  (Z_DIM / BKB)  // 16
#define NT     (TOT / TILE)   // 64 tile-columns
#define NBLK   (NT * (NT + 1) / 2)   // 2080 triangular blocks
#define INV_T  2.0f           // 1/temperature
#define SCL    16.0f          // fp8 pre-scale; logits = acc * INV_T / (SCL*SCL)

typedef __attribute__((ext_vector_type(4))) int   intx4;
typedef __attribute__((ext_vector_type(8))) int   intx8;
typedef __attribute__((ext_vector_type(4))) float floatx4;

#define GLOAD16(g, l)                                                   \
    __builtin_amdgcn_global_load_lds(                                   \
        (const __attribute__((address_space(1))) unsigned int*)(g),     \
        (__attribute__((address_space(3))) unsigned int*)(l), 16, 0, 0)

// ---------------- kernel 1: row-normalize to fp8(e4m3, x16), pos, zero rowsum
__global__ __launch_bounds__(256) void normalize_kernel(
    const float* __restrict__ z1, const float* __restrict__ z2,
    unsigned char* __restrict__ reps, float* __restrict__ pos,
    float* __restrict__ rowsum)
{
    const int row  = blockIdx.x;          // 0..4095
    const int tid  = threadIdx.x;         // 0..255, 8 floats each
    const int lane = tid & 63, wave = tid >> 6;

    if (row < TOT / 256) rowsum[row * 256 + tid] = 0.f;   // fold in memset

    const float4* p1 = (const float4*)(z1 + (size_t)row * Z_DIM);
    const float4* p2 = (const float4*)(z2 + (size_t)row * Z_DIM);
    float4 x0 = p1[tid * 2], x1 = p1[tid * 2 + 1];
    float4 y0 = p2[tid * 2], y1 = p2[tid * 2 + 1];

    float s1 = x0.x*x0.x + x0.y*x0.y + x0.z*x0.z + x0.w*x0.w
             + x1.x*x1.x + x1.y*x1.y + x1.z*x1.z + x1.w*x1.w;
    float s2 = y0.x*y0.x + y0.y*y0.y + y0.z*y0.z + y0.w*y0.w
             + y1.x*y1.x + y1.y*y1.y + y1.z*y1.z + y1.w*y1.w;
    float dd = x0.x*y0.x + x0.y*y0.y + x0.z*y0.z + x0.w*y0.w
             + x1.x*y1.x + x1.y*y1.y + x1.z*y1.z + x1.w*y1.w;

    #pragma unroll
    for (int m = 1; m < 64; m <<= 1) {
        s1 += __shfl_xor(s1, m);
        s2 += __shfl_xor(s2, m);
        dd += __shfl_xor(dd, m);
    }
    __shared__ float red[3][4];
    if (lane == 0) { red[0][wave] = s1; red[1][wave] = s2; red[2][wave] = dd; }
    __syncthreads();
    s1 = red[0][0] + red[0][1] + red[0][2] + red[0][3];
    s2 = red[1][0] + red[1][1] + red[1][2] + red[1][3];
    dd = red[2][0] + red[2][1] + red[2][2] + red[2][3];

    const float inv1 = rsqrtf(s1), inv2 = rsqrtf(s2);
    if (tid == 0) {
        float p = dd * inv1 * inv2 * INV_T;   // pos in full fp32 precision
        pos[row] = p;
        pos[row + N_ROWS] = p;
    }

    const float a = inv1 * SCL, b = inv2 * SCL;
    unsigned int a0 = 0, a1 = 0, b0 = 0, b1 = 0;
    a0 = __builtin_amdgcn_cvt_pk_fp8_f32(x0.x * a, x0.y * a, a0, false);
    a0 = __builtin_amdgcn_cvt_pk_fp8_f32(x0.z * a, x0.w * a, a0, true);
    a1 = __builtin_amdgcn_cvt_pk_fp8_f32(x1.x * a, x1.y * a, a1, false);
    a1 = __builtin_amdgcn_cvt_pk_fp8_f32(x1.z * a, x1.w * a, a1, true);
    b0 = __builtin_amdgcn_cvt_pk_fp8_f32(y0.x * b, y0.y * b, b0, false);
    b0 = __builtin_amdgcn_cvt_pk_fp8_f32(y0.z * b, y0.w * b, b0, true);
    b1 = __builtin_amdgcn_cvt_pk_fp8_f32(y1.x * b, y1.y * b, b1, false);
    b1 = __builtin_amdgcn_cvt_pk_fp8_f32(y1.z * b, y1.w * b, b1, true);
    uint2 pa = {a0, a1}, pb = {b0, b1};
    *(uint2*)(reps + (size_t)row * Z_DIM + tid * 8) = pa;
    *(uint2*)(reps + (size_t)(N_ROWS + row) * Z_DIM + tid * 8) = pb;
}

// ---------------- kernel 2: triangular S = reps@reps^T, MX-fp8 K=128 --------
// Producer/consumer wave specialization + double-buffered LDS. Per 256-thread
// block: 2 producer waves (A-tile / B-tile) issue global_load_lds for tile i+1
// while 2 consumer waves (64-col halves, 8x4 grid of 16x16x128 MFMA over the
// full 128 rows) compute tile i. One __syncthreads per iter: producers' barrier
// drains THEIR loads; consumers carry no vmcnt, so load latency overlaps MFMA.
// Role = (wave + blockIdx)&1 so producer/consumer SIMDs alternate across
// resident blocks. LDS 16B-chunk swizzle: slot = kc ^ (row&7).
__global__ __launch_bounds__(256, 2) void simclr_gemm(
    const unsigned char* __restrict__ reps, float* __restrict__ rowsum)
{
    __shared__ __align__(16) unsigned char L[2][2][TILE * BKB];   // 64 KiB

    // decode linear block id -> lower-triangle (r >= c); bi = c, bj = r
    const int t = blockIdx.x;
    int r = (int)((sqrtf(8.0f * (float)t + 1.0f) - 1.0f) * 0.5f);
    while ((r + 1) * (r + 2) / 2 <= t) ++r;
    while (r * (r + 1) / 2 > t) --r;
    const int bi = t - r * (r + 1) / 2;   // <= bj
    const int bj = r;
    const bool diag = (bi == bj);

    const int tid  = threadIdx.x;
    const int lane = tid & 63, wave = tid >> 6;
    const int quad = lane >> 4, l16 = lane & 15;
    const int sw   = l16 & 7;                     // read-side XOR swizzle
    const int row0 = bi * TILE, col0 = bj * TILE;

    const bool producer = ((wave + blockIdx.x) & 1) == 0;
    const int  half     = wave >> 1;              // producer: A/B; consumer: col half

    if (producer) {
        // chunk c = t*64+lane: row = t*8 + (lane>>3), slot = lane&7,
        // global chunk = slot ^ (row&7)  (t*8 = 0 mod 8 -> lane-only)
        const int grow = lane >> 3;
        const int gkc  = (lane & 7) ^ grow;
        const int tile0 = half ? col0 : row0;
        const unsigned char* gsrc = reps + (size_t)(tile0 + grow) * Z_DIM + gkc * 16;
        const size_t rstep = (size_t)8 * Z_DIM;

        // prologue: tile 0 -> buf 0
        {
            unsigned char* lb = &L[0][half][lane * 16];
            #pragma unroll
            for (int q = 0; q < 16; ++q) GLOAD16(gsrc + q * rstep, lb + q * 1024);
        }
        __syncthreads();
        for (int i = 0; i < NITER; ++i) {
            if (i + 1 < NITER) {
                const unsigned char* g = gsrc + (size_t)(i + 1) * BKB;
                unsigned char* lb = &L[(i + 1) & 1][half][lane * 16];
                #pragma unroll
                for (int q = 0; q < 16; ++q) GLOAD16(g + q * rstep, lb + q * 1024);
            }
            __syncthreads();   // drains this wave's vmcnt -> buf visible next iter
        }
        return;                // no accumulator, no epilogue
    }

    // ---------------- consumer ----------------
    floatx4 acc[8][4];
    #pragma unroll
    for (int i = 0; i < 8; ++i)
        #pragma unroll
        for (int j = 0; j < 4; ++j)
            acc[i][j] = floatx4{0.f, 0.f, 0.f, 0.f};

    __syncthreads();           // matches producer prologue barrier
    for (int i = 0; i < NITER; ++i) {
        const unsigned char* Ab = &L[i & 1][0][0];
        const unsigned char* Bb = &L[i & 1][1][0];

        intx8 bf[4];
        #pragma unroll
        for (int j = 0; j < 4; ++j) {
            const int br = (half * 64 + j * 16 + l16) * BKB;
            intx4 lo = *(const intx4*)&Bb[br + (((quad * 2)     ^ sw) << 4)];
            intx4 hi = *(const intx4*)&Bb[br + (((quad * 2 + 1) ^ sw) << 4)];
            bf[j] = intx8{lo[0], lo[1], lo[2], lo[3], hi[0], hi[1], hi[2], hi[3]};
        }
        #pragma unroll
        for (int fi = 0; fi < 8; ++fi) {
            const int ar = (fi * 16 + l16) * BKB;
            intx4 lo = *(const intx4*)&Ab[ar + (((quad * 2)     ^ sw) << 4)];
            intx4 hi = *(const intx4*)&Ab[ar + (((quad * 2 + 1) ^ sw) << 4)];
            intx8 af = intx8{lo[0], lo[1], lo[2], lo[3], hi[0], hi[1], hi[2], hi[3]};
            #pragma unroll
            for (int j = 0; j < 4; ++j)
                acc[fi][j] = __builtin_amdgcn_mfma_scale_f32_16x16x128_f8f6f4(
                    af, bf[j], acc[fi][j],
                    0, 0,                      // cbsz=fp8(A), blgp=fp8(B)
                    0, 0x7F7F7F7Fu,            // scale_a = 1.0 (E8M0)
                    0, 0x7F7F7F7Fu);           // scale_b = 1.0
        }
        __syncthreads();
    }

    // Epilogue: C/D layout col = lane&15, row = quad*4 + reg.
    // logit = acc * INV_T / SCL^2; |logit| <= 2 so plain exp-sum is safe.
    const float descale = INV_T / (SCL * SCL);   // 1/128
    float scol[4] = {0.f, 0.f, 0.f, 0.f};
    #pragma unroll
    for (int fi = 0; fi < 8; ++fi) {
        const int rbase = row0 + fi * 16 + quad * 4;
        float srow[4] = {0.f, 0.f, 0.f, 0.f};
        #pragma unroll
        for (int j = 0; j < 4; ++j) {
            const int c = col0 + half * 64 + j * 16 + l16;
            #pragma unroll
            for (int rr = 0; rr < 4; ++rr) {
                float e = __expf(acc[fi][j][rr] * descale);
                if (diag && (rbase + rr == c)) e = 0.f;  // exclude self-sim
                srow[rr] += e;
                scol[j]  += e;
            }
        }
        #pragma unroll
        for (int rr = 0; rr < 4; ++rr) {
            #pragma unroll
            for (int m = 1; m < 16; m <<= 1) srow[rr] += __shfl_xor(srow[rr], m);
        }
        if (l16 == 0) {
            #pragma unroll
            for (int rr = 0; rr < 4; ++rr)
                atomicAdd(&rowsum[rbase + rr], srow[rr]);
        }
    }
    if (!diag) {   // symmetry credit: column sums -> mirrored rows
        #pragma unroll
        for (int j = 0; j < 4; ++j) {
            scol[j] += __shfl_xor(scol[j], 16);
            scol[j] += __shfl_xor(scol[j], 32);
        }
        if (quad == 0) {
            #pragma unroll
            for (int j = 0; j < 4; ++j)
                atomicAdd(&rowsum[col0 + half * 64 + j * 16 + l16], scol[j]);
        }
    }
}

// ---------------- kernel 3: mean(log(rowsum) - pos) ----------------
__global__ __launch_bounds__(1024) void finalize_kernel(
    const float* __restrict__ rowsum, const float* __restrict__ pos,
    float* __restrict__ out)
{
    const int tid = threadIdx.x;
    const int lane = tid & 63, wave = tid >> 6;
    float s = 0.f;
    for (int r = tid; r < TOT; r += 1024) s += logf(rowsum[r]) - pos[r];
    #pragma unroll
    for (int m = 1; m < 64; m <<= 1) s += __shfl_xor(s, m);
    __shared__ float red[16];
    if (lane == 0) red[wave] = s;
    __syncthreads();
    if (tid == 0) {
        float t = 0.f;
        #pragma unroll
        for (int w = 0; w < 16; ++w) t += red[w];
        out[0] = t * (1.0f / TOT);
    }
}

extern "C" void kernel_launch(void* const* d_in, const int* in_sizes, int n_in,
                              void* d_out, int out_size, void* d_ws, size_t ws_size,
                              hipStream_t stream)
{
    const float* z1 = (const float*)d_in[0];
    const float* z2 = (const float*)d_in[1];
    float* out = (float*)d_out;

    char* w = (char*)d_ws;
    unsigned char* reps = (unsigned char*)w;                 // 16 MiB fp8 [8192][2048]
    float* pos    = (float*)(w + (size_t)TOT * Z_DIM);       // 32 KiB
    float* rowsum = pos + TOT;                               // 32 KiB

    normalize_kernel<<<N_ROWS, 256, 0, stream>>>(z1, z2, reps, pos, rowsum);
    simclr_gemm<<<NBLK, 256, 0, stream>>>(reps, rowsum);
    finalize_kernel<<<1, 1024, 0, stream>>>(rowsum, pos, out);
}